// Round 11
// baseline (149.963 us; speedup 1.0000x reference)
//
#include <hip/hip_runtime.h>

#define BB 4096
#define TT 512
#define HH 10
#define L2E 1.44269504088896340736f

typedef __fp16 half2_t __attribute__((ext_vector_type(2)));

__device__ __forceinline__ float rcp_(float x) { return __builtin_amdgcn_rcpf(x); }
__device__ __forceinline__ float exp2_(float x) { return __builtin_amdgcn_exp2f(x); }

// ds_swizzle BitMode (operates within each 32-lane group): src = ((lane & and) | or) ^ xor
// offset = xor<<10 | or<<5 | and
#define SWZ(v, off) __int_as_float(__builtin_amdgcn_ds_swizzle(__float_as_int(v), (off)))
#define SWZ_PARTNER 0x20F   // src = (lane&0x0F)|0x10 : pull from hf=1 partner lane

// DPP: quad_perm + row_ror (within 16-lane rows)
template <int CTRL>
__device__ __forceinline__ float dpp_(float v) {
    return __int_as_float(__builtin_amdgcn_update_dpp(
        0, __float_as_int(v), CTRL, 0xf, 0xf, true));
}
#define QP_XOR1 0xB1
#define QP_XOR2 0x4E
#define ROR4    0x124
#define ROR8    0x128

// 32 lanes per batch element (2 elements/wave, 2048 waves = 2/SIMD chip-wide).
// Within a 32-lane group: u = l&15, hf = l>>4. Owner lanes u<10.
//   hf=0 lane u holds gate rows {i: u, f: 10+u};  hf=1 lane u holds {g: 20+u, o: 30+u}.
// Each lane: 2 gate rows x 5 dot2 (f16), 2 trans-pairs. hf0 pulls sigma(2g), sigma(o)
// from partner (one 2-swizzle episode), updates c, computes h_u. 10-swizzle broadcast
// of h to all 32 lanes. Regressor lives in hf=1 lanes (5 dot2 + 4-DPP 16-lane reduce);
// lane 16 stores the float4 output. tanh via 2*sigma(2z)-1.
__global__ __launch_bounds__(64) void lstm32_kernel(
    const float* __restrict__ x, const float* __restrict__ h0, const float* __restrict__ c0,
    const float* __restrict__ W_ih, const float* __restrict__ W_hh,
    const float* __restrict__ b_ih, const float* __restrict__ b_hh,
    const float* __restrict__ W1, const float* __restrict__ b1,
    const float* __restrict__ W2, const float* __restrict__ b2,
    float* __restrict__ out)
{
    const int lane = threadIdx.x;          // block = 64 = one wave = 2 elements
    const int l = lane & 31;               // lane within 32-lane group
    const int u = l & 15;
    const int hf = l >> 4;                 // half: 0 -> {i,f}, 1 -> {g,o}
    const int e = blockIdx.x * 2 + (lane >> 5);

    const bool own = (u < HH);
    const float m = own ? 1.0f : 0.0f;
    const int uu = own ? u : 0;

    // ---- per-lane weights: 2 gate rows (f16-packed) ----
    const int rA = hf ? 20 + uu : uu;        // i or g
    const int rB = hf ? 30 + uu : 10 + uu;   // f or o
    half2_t WA[5], WB[5];
    {
        const float2* pA = (const float2*)(W_hh + rA * HH);
        const float2* pB = (const float2*)(W_hh + rB * HH);
#pragma unroll
        for (int p = 0; p < 5; p++) {
            float2 wa = pA[p], wb = pB[p];
            WA[p] = __builtin_amdgcn_cvt_pkrtz(wa.x * m, wa.y * m);
            WB[p] = __builtin_amdgcn_cvt_pkrtz(wb.x * m, wb.y * m);
        }
    }
    const float bA = b_ih[rA] + b_hh[rA];
    const float bB = b_ih[rB] + b_hh[rB];
    const float wihA = W_ih[rA], wihB = W_ih[rB];
    const float negmA = hf ? -2.0f * L2E : -L2E;   // g rows are tanh: sigma(2z)
    const float negmB = -L2E;                      // f/o rows sigmoid

    // ---- regressor row u, lives in hf=1 lanes ----
    const float mr = (hf && own) ? 1.0f : 0.0f;
    half2_t W1p[5];
    {
        const float2* rp = (const float2*)(W1 + uu * HH);
#pragma unroll
        for (int p = 0; p < 5; p++) {
            float2 w = rp[p];
            W1p[p] = __builtin_amdgcn_cvt_pkrtz(w.x * mr, w.y * mr);
        }
    }
    const float b1r = mr * b1[uu];
    const float W2r = mr * W2[uu];
    const float b2s = b2[0];

    // ---- state ----
    float c = (own && !hf) ? c0[e * HH + u] : 0.0f;
    float hb[10];
#pragma unroll
    for (int j = 0; j < 10; j++) hb[j] = h0[e * HH + j];
    half2_t hp[5];
#pragma unroll
    for (int p = 0; p < 5; p++) hp[p] = __builtin_amdgcn_cvt_pkrtz(hb[2 * p], hb[2 * p + 1]);

    const float4* xq  = (const float4*)(x + (size_t)e * TT);
    float4*       ob4 = (float4*)(out + (size_t)e * TT);

    float4 xc = xq[0];
    for (int gb = 0; gb < TT / 4; gb++) {
        float4 xn = xq[(gb + 1 < TT / 4) ? gb + 1 : gb];
        float4 outv;

#pragma unroll
        for (int r4 = 0; r4 < 4; r4++) {
            const float xv = (r4 == 0) ? xc.x : (r4 == 1) ? xc.y : (r4 == 2) ? xc.z : xc.w;

            // ---- 2 lane-local gate rows ----
            float gA = fmaf(xv, wihA, bA);
            float gB = fmaf(xv, wihB, bB);
#pragma unroll
            for (int p = 0; p < 5; p++) {
                gA = __builtin_amdgcn_fdot2(hp[p], WA[p], gA, false);
                gB = __builtin_amdgcn_fdot2(hp[p], WB[p], gB, false);
            }
            const float aA = rcp_(1.0f + exp2_(gA * negmA));   // i (hf0) / sigma(2g) (hf1)
            const float aB = rcp_(1.0f + exp2_(gB * negmB));   // f (hf0) / o        (hf1)

            // ---- gather partner's g,o into hf0 owners (one LDS episode) ----
            const float ag = SWZ(aA, SWZ_PARTNER);   // sigma(2*z_g)
            const float ao = SWZ(aB, SWZ_PARTNER);   // sigma(z_o)

            // ---- c/h update (meaningful in hf0 owner lanes): tanh = 2*sigma(2z)-1 ----
            const float cn = fmaf(aB, c, fmaf(2.0f, aA * ag, -aA));
            c = cn;
            const float t = rcp_(1.0f + exp2_(cn * (-2.0f * L2E)));
            const float hq = ao * fmaf(2.0f, t, -1.0f);

            // ---- broadcast h_u from lanes 0..9 to all 32 lanes ----
            hb[0] = SWZ(hq, 0 << 5); hb[1] = SWZ(hq, 1 << 5);
            hb[2] = SWZ(hq, 2 << 5); hb[3] = SWZ(hq, 3 << 5);
            hb[4] = SWZ(hq, 4 << 5); hb[5] = SWZ(hq, 5 << 5);
            hb[6] = SWZ(hq, 6 << 5); hb[7] = SWZ(hq, 7 << 5);
            hb[8] = SWZ(hq, 8 << 5); hb[9] = SWZ(hq, 9 << 5);
#pragma unroll
            for (int p = 0; p < 5; p++)
                hp[p] = __builtin_amdgcn_cvt_pkrtz(hb[2 * p], hb[2 * p + 1]);

            // ---- regressor in hf1 lanes: relu(W1_u.h + b1_u)*W2_u, 16-lane DPP reduce ----
            float a = b1r;
#pragma unroll
            for (int p = 0; p < 5; p++)
                a = __builtin_amdgcn_fdot2(hp[p], W1p[p], a, false);
            float part = fmaxf(a, 0.0f) * W2r;
            part += dpp_<QP_XOR1>(part);
            part += dpp_<QP_XOR2>(part);
            part += dpp_<ROR4>(part);
            part += dpp_<ROR8>(part);
            const float s = part + b2s + xv;

            if (r4 == 0) outv.x = s;
            else if (r4 == 1) outv.y = s;
            else if (r4 == 2) outv.z = s;
            else outv.w = s;
        }

        if (l == 16) ob4[gb] = outv;   // hf1 row holds the reduced sum; one store lane/element
        xc = xn;
    }
}

extern "C" void kernel_launch(void* const* d_in, const int* in_sizes, int n_in,
                              void* d_out, int out_size, void* d_ws, size_t ws_size,
                              hipStream_t stream) {
    const float* x    = (const float*)d_in[0];
    const float* h0   = (const float*)d_in[1];
    const float* c0   = (const float*)d_in[2];
    const float* W_ih = (const float*)d_in[3];
    const float* W_hh = (const float*)d_in[4];
    const float* b_ih = (const float*)d_in[5];
    const float* b_hh = (const float*)d_in[6];
    const float* W1   = (const float*)d_in[7];
    const float* b1   = (const float*)d_in[8];
    const float* W2   = (const float*)d_in[9];
    const float* b2   = (const float*)d_in[10];
    float* out = (float*)d_out;

    dim3 grid(BB * 32 / 64);   // 2048 blocks: 8 waves/CU (2 per SIMD)
    dim3 block(64);
    lstm32_kernel<<<grid, block, 0, stream>>>(x, h0, c0, W_ih, W_hh, b_ih, b_hh,
                                              W1, b1, W2, b2, out);
}

// Round 12
// 124.562 us; speedup vs baseline: 1.2039x; 1.2039x over previous
//
#include <hip/hip_runtime.h>

#define BB 4096
#define TT 512
#define HH 10
#define L2E 1.44269504088896340736f

typedef __fp16 half2_t __attribute__((ext_vector_type(2)));

__device__ __forceinline__ float rcp_(float x) { return __builtin_amdgcn_rcpf(x); }
__device__ __forceinline__ float exp2_(float x) { return __builtin_amdgcn_exp2f(x); }

// DPP helpers. quad_perm ctrl 0x00-0xFF; row_ror:N = 0x120|N (dst[i] = src[(i+N)&15],
// within each 16-lane row). update_dpp(old, src, ctrl, row_mask, bank_mask, bound):
// lanes outside row/bank masks keep `old` — used to merge rotations into one register.
template <int CTRL, int BANK = 0xF>
__device__ __forceinline__ int dppi_(int old, int src) {
    return __builtin_amdgcn_update_dpp(old, src, CTRL, 0xF, BANK, true);
}
template <int CTRL>
__device__ __forceinline__ float dpp_(float v) {
    return __int_as_float(__builtin_amdgcn_update_dpp(
        0, __float_as_int(v), CTRL, 0xF, 0xF, true));
}
#define QP_XOR1 0xB1   // [1,0,3,2]
#define QP_XOR2 0x4E   // [2,3,0,1]
#define QP_B0   0x00   // broadcast quad lane 0
#define QP_B2   0xAA   // broadcast quad lane 2
#define ROR4    0x124
#define ROR8    0x128
#define ROR12   0x12C

// 16 lanes per batch element (4 elements/wave, 1024 waves = 1/SIMD chip-wide).
// Owner lane u<10 holds ALL FOUR gate rows of its unit {u,10+u,20+u,30+u} (f16-packed
// for v_dot2_f32_f16). tanh rows evaluated as sigma(2z), recovered via 2s-1.
// ZERO LDS ops in the loop: the h all-gather is pure DPP — pair-pack h via quad_perm
// XOR1 + cvt_pkrtz (pk_j in lanes 2j,2j+1), then two quad-broadcasts (A: quad-lane 0,
// B: quad-lane 2) + 15 bank-masked row_ror merges give every lane all five packed
// pairs. Regressor reduce is the (already-validated) DPP xor/ror tree.
__global__ __launch_bounds__(64) void lstm16dpp_kernel(
    const float* __restrict__ x, const float* __restrict__ h0, const float* __restrict__ c0,
    const float* __restrict__ W_ih, const float* __restrict__ W_hh,
    const float* __restrict__ b_ih, const float* __restrict__ b_hh,
    const float* __restrict__ W1, const float* __restrict__ b1,
    const float* __restrict__ W2, const float* __restrict__ b2,
    float* __restrict__ out)
{
    const int lane = threadIdx.x;          // block = 64 = one wave = 4 elements
    const int l = lane & 15;               // lane within 16-lane group
    const int e = blockIdx.x * 4 + (lane >> 4);

    const bool owner = (l < HH);
    const int u = owner ? l : 0;
    const float m = owner ? 1.0f : 0.0f;

    // ---- per-lane weights: all 4 gate rows of unit u (f16-packed) ----
    const int ri = u, rf = 10 + u, rg = 20 + u, ro = 30 + u;
    half2_t Wi[5], Wf[5], Wg[5], Wo[5];
    {
        const float2* pi = (const float2*)(W_hh + ri * HH);
        const float2* pf = (const float2*)(W_hh + rf * HH);
        const float2* pg = (const float2*)(W_hh + rg * HH);
        const float2* po = (const float2*)(W_hh + ro * HH);
#pragma unroll
        for (int p = 0; p < 5; p++) {
            float2 wi = pi[p], wf = pf[p], wg = pg[p], wo = po[p];
            Wi[p] = __builtin_amdgcn_cvt_pkrtz(wi.x * m, wi.y * m);
            Wf[p] = __builtin_amdgcn_cvt_pkrtz(wf.x * m, wf.y * m);
            Wg[p] = __builtin_amdgcn_cvt_pkrtz(wg.x * m, wg.y * m);
            Wo[p] = __builtin_amdgcn_cvt_pkrtz(wo.x * m, wo.y * m);
        }
    }
    const float bi = b_ih[ri] + b_hh[ri];
    const float bf = b_ih[rf] + b_hh[rf];
    const float bg = b_ih[rg] + b_hh[rg];
    const float bo = b_ih[ro] + b_hh[ro];
    const float wii = W_ih[ri], wif = W_ih[rf], wig = W_ih[rg], wio = W_ih[ro];

    // ---- regressor row u ----
    half2_t W1p[5];
    {
        const float2* rp = (const float2*)(W1 + u * HH);
#pragma unroll
        for (int p = 0; p < 5; p++) {
            float2 w = rp[p];
            W1p[p] = __builtin_amdgcn_cvt_pkrtz(w.x * m, w.y * m);
        }
    }
    const float b1r = m * b1[u];
    const float W2r = m * W2[u];
    const float b2s = b2[0];

    const bool oddlane = (lane & 1);

    // ---- state ----
    float c = owner ? c0[e * HH + u] : 0.0f;
    half2_t hp[5];
    {
        float hb[10];
#pragma unroll
        for (int j = 0; j < 10; j++) hb[j] = h0[e * HH + j];
#pragma unroll
        for (int p = 0; p < 5; p++) hp[p] = __builtin_amdgcn_cvt_pkrtz(hb[2 * p], hb[2 * p + 1]);
    }

    const float4* xq  = (const float4*)(x + (size_t)e * TT);
    float4*       ob4 = (float4*)(out + (size_t)e * TT);

    float4 xc = xq[0];
    for (int gb = 0; gb < TT / 4; gb++) {
        float4 xn = xq[(gb + 1 < TT / 4) ? gb + 1 : gb];
        float4 outv;

#pragma unroll
        for (int r4 = 0; r4 < 4; r4++) {
            const float xv = (r4 == 0) ? xc.x : (r4 == 1) ? xc.y : (r4 == 2) ? xc.z : xc.w;

            // ---- 4 lane-local gate rows: bias + x*wih + h.W via dot2 ----
            float gi = fmaf(xv, wii, bi);
            float gf = fmaf(xv, wif, bf);
            float gg = fmaf(xv, wig, bg);
            float go = fmaf(xv, wio, bo);
#pragma unroll
            for (int p = 0; p < 5; p++) {
                gi = __builtin_amdgcn_fdot2(hp[p], Wi[p], gi, false);
                gf = __builtin_amdgcn_fdot2(hp[p], Wf[p], gf, false);
                gg = __builtin_amdgcn_fdot2(hp[p], Wg[p], gg, false);
                go = __builtin_amdgcn_fdot2(hp[p], Wo[p], go, false);
            }
            const float ai = rcp_(1.0f + exp2_(gi * (-L2E)));
            const float af = rcp_(1.0f + exp2_(gf * (-L2E)));
            const float ag = rcp_(1.0f + exp2_(gg * (-2.0f * L2E)));  // sigma(2z)
            const float ao = rcp_(1.0f + exp2_(go * (-L2E)));

            // ---- c/h update: tanh(z) = 2*sigma(2z)-1 folded in ----
            const float cn = fmaf(af, c, fmaf(2.0f, ai * ag, -ai));
            c = cn;
            const float t = rcp_(1.0f + exp2_(cn * (-2.0f * L2E)));
            const float hq = ao * fmaf(2.0f, t, -1.0f);

            // ---- pure-DPP packed h broadcast (no LDS) ----
            // pair-pack: lanes 2j,2j+1 both build pk_j = (h_2j, h_2j+1)
            const float hq_p = dpp_<QP_XOR1>(hq);
            const float plo = oddlane ? hq_p : hq;
            const float phi = oddlane ? hq : hq_p;
            half2_t pkh = __builtin_amdgcn_cvt_pkrtz(plo, phi);
            const int pk = *(const int*)&pkh;
            // A: each quad sees its lane0 (pk0/pk2/pk4 in quads 0/1/2)
            // B: each quad sees its lane2 (pk1/pk3 in quads 0/1)
            const int A = dppi_<QP_B0>(0, pk);
            const int B = dppi_<QP_B2>(0, pk);
            // spread quad q's value to the other three banks via masked row_ror
            int h0i = A;                                 // pk0 @ quad0
            h0i = dppi_<ROR12, 0x2>(h0i, A);
            h0i = dppi_<ROR8,  0x4>(h0i, A);
            h0i = dppi_<ROR4,  0x8>(h0i, A);
            int h1i = B;                                 // pk1 @ quad0
            h1i = dppi_<ROR12, 0x2>(h1i, B);
            h1i = dppi_<ROR8,  0x4>(h1i, B);
            h1i = dppi_<ROR4,  0x8>(h1i, B);
            int h2i = A;                                 // pk2 @ quad1
            h2i = dppi_<ROR4,  0x1>(h2i, A);
            h2i = dppi_<ROR12, 0x4>(h2i, A);
            h2i = dppi_<ROR8,  0x8>(h2i, A);
            int h3i = B;                                 // pk3 @ quad1
            h3i = dppi_<ROR4,  0x1>(h3i, B);
            h3i = dppi_<ROR12, 0x4>(h3i, B);
            h3i = dppi_<ROR8,  0x8>(h3i, B);
            int h4i = A;                                 // pk4 @ quad2
            h4i = dppi_<ROR8,  0x1>(h4i, A);
            h4i = dppi_<ROR4,  0x2>(h4i, A);
            h4i = dppi_<ROR12, 0x8>(h4i, A);
            hp[0] = *(const half2_t*)&h0i;
            hp[1] = *(const half2_t*)&h1i;
            hp[2] = *(const half2_t*)&h2i;
            hp[3] = *(const half2_t*)&h3i;
            hp[4] = *(const half2_t*)&h4i;

            // ---- regressor: relu(W1_u.h + b1_u)*W2_u, 16-lane DPP reduce ----
            float a = b1r;
#pragma unroll
            for (int p = 0; p < 5; p++)
                a = __builtin_amdgcn_fdot2(hp[p], W1p[p], a, false);
            float part = fmaxf(a, 0.0f) * W2r;
            part += dpp_<QP_XOR1>(part);
            part += dpp_<QP_XOR2>(part);
            part += dpp_<ROR4>(part);
            part += dpp_<ROR8>(part);
            const float s = part + b2s + xv;

            if (r4 == 0) outv.x = s;
            else if (r4 == 1) outv.y = s;
            else if (r4 == 2) outv.z = s;
            else outv.w = s;
        }

        if (l == 0) ob4[gb] = outv;
        xc = xn;
    }
}

extern "C" void kernel_launch(void* const* d_in, const int* in_sizes, int n_in,
                              void* d_out, int out_size, void* d_ws, size_t ws_size,
                              hipStream_t stream) {
    const float* x    = (const float*)d_in[0];
    const float* h0   = (const float*)d_in[1];
    const float* c0   = (const float*)d_in[2];
    const float* W_ih = (const float*)d_in[3];
    const float* W_hh = (const float*)d_in[4];
    const float* b_ih = (const float*)d_in[5];
    const float* b_hh = (const float*)d_in[6];
    const float* W1   = (const float*)d_in[7];
    const float* b1   = (const float*)d_in[8];
    const float* W2   = (const float*)d_in[9];
    const float* b2   = (const float*)d_in[10];
    float* out = (float*)d_out;

    dim3 grid(BB * 16 / 64);   // 1024 blocks: 4 waves/CU (1 per SIMD)
    dim3 block(64);
    lstm16dpp_kernel<<<grid, block, 0, stream>>>(x, h0, c0, W_ih, W_hh, b_ih, b_hh,
                                                 W1, b1, W2, b2, out);
}

// Round 13
// 117.339 us; speedup vs baseline: 1.2780x; 1.0616x over previous
//
#include <hip/hip_runtime.h>

#define BB 4096
#define TT 512
#define HH 10
#define L2E 1.44269504088896340736f

typedef __fp16 half2_t __attribute__((ext_vector_type(2)));

__device__ __forceinline__ float rcp_(float x) { return __builtin_amdgcn_rcpf(x); }
__device__ __forceinline__ float exp2_(float x) { return __builtin_amdgcn_exp2f(x); }

// DPP helpers. quad_perm ctrl 0x00-0xFF; row_ror:N = 0x120|N (dst[i] = src[(i+N)&15],
// within each 16-lane row). update_dpp(old, src, ctrl, row_mask, bank_mask, bound):
// lanes outside row/bank masks keep `old` — used to merge rotations into one register.
template <int CTRL, int BANK = 0xF>
__device__ __forceinline__ int dppi_(int old, int src) {
    return __builtin_amdgcn_update_dpp(old, src, CTRL, 0xF, BANK, true);
}
template <int CTRL>
__device__ __forceinline__ float dpp_(float v) {
    return __int_as_float(__builtin_amdgcn_update_dpp(
        0, __float_as_int(v), CTRL, 0xF, 0xF, true));
}
#define QP_XOR1 0xB1   // [1,0,3,2]
#define QP_XOR2 0x4E   // [2,3,0,1]
#define QP_B0   0x00   // broadcast quad lane 0
#define QP_B2   0xAA   // broadcast quad lane 2
#define ROR4    0x124
#define ROR8    0x128
#define ROR12   0x12C

// 16 lanes per batch element (4 elements/wave, 1024 waves = 1/SIMD chip-wide).
// Owner lane u<10 holds ALL FOUR gate rows of its unit {u,10+u,20+u,30+u}, f16-packed
// for v_dot2_f32_f16 and PRE-SCALED by -log2e (i,f,o rows) / -2log2e (g row) so the
// accumulated gate value feeds exp2 directly. Activations use merged-rcp forms:
//   sigma(i)*tanh(g) = (1-G)/((1+A)(1+G)),  A=2^gi', G=2^gg'
//   h = sigma(o)*tanh(c) = (1-T)/((1+O)(1+T)), T=2^(-2*log2e*c)
// -> 5 exp2 + 3 rcp per step (was 5+5). ZERO LDS ops in the loop: h all-gather is the
// validated pure-DPP tree; regressor reduce is the DPP xor/ror tree with b2 folded
// into a lane-0 seed.
__global__ __launch_bounds__(64) void lstm16dpp2_kernel(
    const float* __restrict__ x, const float* __restrict__ h0, const float* __restrict__ c0,
    const float* __restrict__ W_ih, const float* __restrict__ W_hh,
    const float* __restrict__ b_ih, const float* __restrict__ b_hh,
    const float* __restrict__ W1, const float* __restrict__ b1,
    const float* __restrict__ W2, const float* __restrict__ b2,
    float* __restrict__ out)
{
    const int lane = threadIdx.x;          // block = 64 = one wave = 4 elements
    const int l = lane & 15;               // lane within 16-lane group
    const int e = blockIdx.x * 4 + (lane >> 4);

    const bool owner = (l < HH);
    const int u = owner ? l : 0;
    const float m = owner ? 1.0f : 0.0f;

    // ---- per-lane weights: all 4 gate rows of unit u (f16-packed, pre-scaled) ----
    const int ri = u, rf = 10 + u, rg = 20 + u, ro = 30 + u;
    const float sS = -L2E;          // sigmoid rows: exp2 of -log2e*z
    const float sG = -2.0f * L2E;   // tanh row: exp2 of -2log2e*z
    half2_t Wi[5], Wf[5], Wg[5], Wo[5];
    {
        const float2* pi = (const float2*)(W_hh + ri * HH);
        const float2* pf = (const float2*)(W_hh + rf * HH);
        const float2* pg = (const float2*)(W_hh + rg * HH);
        const float2* po = (const float2*)(W_hh + ro * HH);
#pragma unroll
        for (int p = 0; p < 5; p++) {
            float2 wi = pi[p], wf = pf[p], wg = pg[p], wo = po[p];
            Wi[p] = __builtin_amdgcn_cvt_pkrtz(wi.x * m * sS, wi.y * m * sS);
            Wf[p] = __builtin_amdgcn_cvt_pkrtz(wf.x * m * sS, wf.y * m * sS);
            Wg[p] = __builtin_amdgcn_cvt_pkrtz(wg.x * m * sG, wg.y * m * sG);
            Wo[p] = __builtin_amdgcn_cvt_pkrtz(wo.x * m * sS, wo.y * m * sS);
        }
    }
    const float bi = (b_ih[ri] + b_hh[ri]) * sS;
    const float bf = (b_ih[rf] + b_hh[rf]) * sS;
    const float bg = (b_ih[rg] + b_hh[rg]) * sG;
    const float bo = (b_ih[ro] + b_hh[ro]) * sS;
    const float wii = W_ih[ri] * sS, wif = W_ih[rf] * sS;
    const float wig = W_ih[rg] * sG, wio = W_ih[ro] * sS;

    // ---- regressor row u ----
    half2_t W1p[5];
    {
        const float2* rp = (const float2*)(W1 + u * HH);
#pragma unroll
        for (int p = 0; p < 5; p++) {
            float2 w = rp[p];
            W1p[p] = __builtin_amdgcn_cvt_pkrtz(w.x * m, w.y * m);
        }
    }
    const float b1r = m * b1[u];
    const float W2r = m * W2[u];
    const float seedb = (l == 0) ? b2[0] : 0.0f;   // b2 folded into lane-0 reduce seed

    const bool oddlane = (lane & 1);

    // ---- state ----
    float c = owner ? c0[e * HH + u] : 0.0f;
    half2_t hp[5];
    {
        float hb[10];
#pragma unroll
        for (int j = 0; j < 10; j++) hb[j] = h0[e * HH + j];
#pragma unroll
        for (int p = 0; p < 5; p++) hp[p] = __builtin_amdgcn_cvt_pkrtz(hb[2 * p], hb[2 * p + 1]);
    }

    const float4* xq  = (const float4*)(x + (size_t)e * TT);
    float4*       ob4 = (float4*)(out + (size_t)e * TT);

    float4 xc = xq[0];
    for (int gb = 0; gb < TT / 4; gb++) {
        const int gbn = (gb + 1) & (TT / 4 - 1);   // wrap: last prefetch reads block 0
        float4 xn = xq[gbn];
        float4 outv;

#pragma unroll
        for (int r4 = 0; r4 < 4; r4++) {
            const float xv = (r4 == 0) ? xc.x : (r4 == 1) ? xc.y : (r4 == 2) ? xc.z : xc.w;

            // ---- 4 lane-local gate rows (pre-scaled accumulators) ----
            float gi = fmaf(xv, wii, bi);
            float gf = fmaf(xv, wif, bf);
            float gg = fmaf(xv, wig, bg);
            float go = fmaf(xv, wio, bo);
#pragma unroll
            for (int p = 0; p < 5; p++) {
                gi = __builtin_amdgcn_fdot2(hp[p], Wi[p], gi, false);
                gf = __builtin_amdgcn_fdot2(hp[p], Wf[p], gf, false);
                gg = __builtin_amdgcn_fdot2(hp[p], Wg[p], gg, false);
                go = __builtin_amdgcn_fdot2(hp[p], Wo[p], go, false);
            }
            const float A = exp2_(gi);
            const float F = exp2_(gf);
            const float G = exp2_(gg);
            const float O = exp2_(go);

            // ---- merged-rcp update: cn = sigma(f)*c + sigma(i)*tanh(g) ----
            const float af = rcp_(1.0f + F);
            const float q  = (1.0f - G) * rcp_((1.0f + A) * (1.0f + G));
            const float cn = fmaf(af, c, q);
            c = cn;
            const float T  = exp2_(cn * (-2.0f * L2E));
            const float hq = (1.0f - T) * rcp_((1.0f + O) * (1.0f + T));

            // ---- pure-DPP packed h broadcast (no LDS) ----
            const float hq_p = dpp_<QP_XOR1>(hq);
            const float plo = oddlane ? hq_p : hq;
            const float phi = oddlane ? hq : hq_p;
            half2_t pkh = __builtin_amdgcn_cvt_pkrtz(plo, phi);
            const int pk = *(const int*)&pkh;
            const int A_ = dppi_<QP_B0>(0, pk);   // quad q sees pk_{2q}
            const int B_ = dppi_<QP_B2>(0, pk);   // quad q sees pk_{2q+1}
            int h0i = A_;                          // pk0 @ quad0
            h0i = dppi_<ROR12, 0x2>(h0i, A_);
            h0i = dppi_<ROR8,  0x4>(h0i, A_);
            h0i = dppi_<ROR4,  0x8>(h0i, A_);
            int h1i = B_;                          // pk1 @ quad0
            h1i = dppi_<ROR12, 0x2>(h1i, B_);
            h1i = dppi_<ROR8,  0x4>(h1i, B_);
            h1i = dppi_<ROR4,  0x8>(h1i, B_);
            int h2i = A_;                          // pk2 @ quad1
            h2i = dppi_<ROR4,  0x1>(h2i, A_);
            h2i = dppi_<ROR12, 0x4>(h2i, A_);
            h2i = dppi_<ROR8,  0x8>(h2i, A_);
            int h3i = B_;                          // pk3 @ quad1
            h3i = dppi_<ROR4,  0x1>(h3i, B_);
            h3i = dppi_<ROR12, 0x4>(h3i, B_);
            h3i = dppi_<ROR8,  0x8>(h3i, B_);
            int h4i = A_;                          // pk4 @ quad2
            h4i = dppi_<ROR8,  0x1>(h4i, A_);
            h4i = dppi_<ROR4,  0x2>(h4i, A_);
            h4i = dppi_<ROR12, 0x8>(h4i, A_);
            hp[0] = *(const half2_t*)&h0i;
            hp[1] = *(const half2_t*)&h1i;
            hp[2] = *(const half2_t*)&h2i;
            hp[3] = *(const half2_t*)&h3i;
            hp[4] = *(const half2_t*)&h4i;

            // ---- regressor: relu(W1_u.h + b1_u)*W2_u (+b2 seed), 16-lane DPP reduce ----
            float a = b1r;
#pragma unroll
            for (int p = 0; p < 5; p++)
                a = __builtin_amdgcn_fdot2(hp[p], W1p[p], a, false);
            float part = fmaf(fmaxf(a, 0.0f), W2r, seedb);
            part += dpp_<QP_XOR1>(part);
            part += dpp_<QP_XOR2>(part);
            part += dpp_<ROR4>(part);
            part += dpp_<ROR8>(part);
            const float s = part + xv;

            if (r4 == 0) outv.x = s;
            else if (r4 == 1) outv.y = s;
            else if (r4 == 2) outv.z = s;
            else outv.w = s;
        }

        if (l == 0) ob4[gb] = outv;
        xc = xn;
    }
}

extern "C" void kernel_launch(void* const* d_in, const int* in_sizes, int n_in,
                              void* d_out, int out_size, void* d_ws, size_t ws_size,
                              hipStream_t stream) {
    const float* x    = (const float*)d_in[0];
    const float* h0   = (const float*)d_in[1];
    const float* c0   = (const float*)d_in[2];
    const float* W_ih = (const float*)d_in[3];
    const float* W_hh = (const float*)d_in[4];
    const float* b_ih = (const float*)d_in[5];
    const float* b_hh = (const float*)d_in[6];
    const float* W1   = (const float*)d_in[7];
    const float* b1   = (const float*)d_in[8];
    const float* W2   = (const float*)d_in[9];
    const float* b2   = (const float*)d_in[10];
    float* out = (float*)d_out;

    dim3 grid(BB * 16 / 64);   // 1024 blocks: 4 waves/CU (1 per SIMD)
    dim3 block(64);
    lstm16dpp2_kernel<<<grid, block, 0, stream>>>(x, h0, c0, W_ih, W_hh, b_ih, b_hh,
                                                  W1, b1, W2, b2, out);
}

// Round 14
// 97.478 us; speedup vs baseline: 1.5384x; 1.2038x over previous
//
#include <hip/hip_runtime.h>

#define BB 4096
#define TT 512
#define HH 10
#define L2E 1.44269504088896340736f

typedef __fp16 half2_t __attribute__((ext_vector_type(2)));

__device__ __forceinline__ float rcp_(float x) { return __builtin_amdgcn_rcpf(x); }
__device__ __forceinline__ float exp2_(float x) { return __builtin_amdgcn_exp2f(x); }

// DPP helpers. quad_perm ctrl 0x00-0xFF; row_ror:N = 0x120|N (dst[i] = src[(i+N)&15],
// within each 16-lane row). update_dpp(old, src, ctrl, row_mask, bank_mask, bound):
// lanes outside row/bank masks keep `old` — used to merge rotations into one register.
template <int CTRL, int BANK = 0xF>
__device__ __forceinline__ int dppi_(int old, int src) {
    return __builtin_amdgcn_update_dpp(old, src, CTRL, 0xF, BANK, true);
}
template <int CTRL>
__device__ __forceinline__ float dpp_(float v) {
    return __int_as_float(__builtin_amdgcn_update_dpp(
        0, __float_as_int(v), CTRL, 0xF, 0xF, true));
}
#define QP_XOR1 0xB1   // [1,0,3,2]
#define QP_XOR2 0x4E   // [2,3,0,1]
#define QP_B0   0x00   // broadcast quad lane 0
#define QP_B2   0xAA   // broadcast quad lane 2
#define ROR4    0x124
#define ROR8    0x128
#define ROR12   0x12C

// 16 lanes per batch element (4 elements/wave, 1024 waves = 1/SIMD chip-wide).
// Owner lane u<10 holds all 4 gate rows {u,10+u,20+u,30+u}, f16-packed for
// v_dot2_f32_f16, PRE-SCALED by -log2e / -2log2e so accumulators feed exp2 directly.
// Merged-rcp activations: sigma(i)tanh(g) = (1-G)/((1+A)(1+G)); h = (1-T)/((1+O)(1+T)).
// SOFTWARE-PIPELINED REGRESSOR: at iteration t, hp still holds h(t-1), so the
// step-(t-1) regressor executes between step-t's gate dot2s and its serial
// act->c->h->broadcast chain, filling the chain's stall slots. Output slots shift by
// one sub-step (slot (r4+3)&3); float4 stored at r4==0 of the NEXT gb; epilogue does
// step 511. Broadcast tree trimmed: bank-3 (lanes 12-15, zero-weight) merges dropped,
// pair-pack sels dropped (only even quad-lanes are broadcast sources).
__global__ __launch_bounds__(64) void lstm16pipe_kernel(
    const float* __restrict__ x, const float* __restrict__ h0, const float* __restrict__ c0,
    const float* __restrict__ W_ih, const float* __restrict__ W_hh,
    const float* __restrict__ b_ih, const float* __restrict__ b_hh,
    const float* __restrict__ W1, const float* __restrict__ b1,
    const float* __restrict__ W2, const float* __restrict__ b2,
    float* __restrict__ out)
{
    const int lane = threadIdx.x;          // block = 64 = one wave = 4 elements
    const int l = lane & 15;               // lane within 16-lane group
    const int e = blockIdx.x * 4 + (lane >> 4);

    const bool owner = (l < HH);
    const int u = owner ? l : 0;
    const float m = owner ? 1.0f : 0.0f;

    // ---- per-lane weights: all 4 gate rows of unit u (f16-packed, pre-scaled) ----
    const int ri = u, rf = 10 + u, rg = 20 + u, ro = 30 + u;
    const float sS = -L2E;          // sigmoid rows: exp2 of -log2e*z
    const float sG = -2.0f * L2E;   // tanh row: exp2 of -2log2e*z
    half2_t Wi[5], Wf[5], Wg[5], Wo[5];
    {
        const float2* pi = (const float2*)(W_hh + ri * HH);
        const float2* pf = (const float2*)(W_hh + rf * HH);
        const float2* pg = (const float2*)(W_hh + rg * HH);
        const float2* po = (const float2*)(W_hh + ro * HH);
#pragma unroll
        for (int p = 0; p < 5; p++) {
            float2 wi = pi[p], wf = pf[p], wg = pg[p], wo = po[p];
            Wi[p] = __builtin_amdgcn_cvt_pkrtz(wi.x * m * sS, wi.y * m * sS);
            Wf[p] = __builtin_amdgcn_cvt_pkrtz(wf.x * m * sS, wf.y * m * sS);
            Wg[p] = __builtin_amdgcn_cvt_pkrtz(wg.x * m * sG, wg.y * m * sG);
            Wo[p] = __builtin_amdgcn_cvt_pkrtz(wo.x * m * sS, wo.y * m * sS);
        }
    }
    const float bi = (b_ih[ri] + b_hh[ri]) * sS;
    const float bf = (b_ih[rf] + b_hh[rf]) * sS;
    const float bg = (b_ih[rg] + b_hh[rg]) * sG;
    const float bo = (b_ih[ro] + b_hh[ro]) * sS;
    const float wii = W_ih[ri] * sS, wif = W_ih[rf] * sS;
    const float wig = W_ih[rg] * sG, wio = W_ih[ro] * sS;

    // ---- regressor row u ----
    half2_t W1p[5];
    {
        const float2* rp = (const float2*)(W1 + u * HH);
#pragma unroll
        for (int p = 0; p < 5; p++) {
            float2 w = rp[p];
            W1p[p] = __builtin_amdgcn_cvt_pkrtz(w.x * m, w.y * m);
        }
    }
    const float b1r = m * b1[u];
    const float W2r = m * W2[u];
    const float seedb = (l == 0) ? b2[0] : 0.0f;   // b2 folded into lane-0 reduce seed

    // ---- state ----
    float c = owner ? c0[e * HH + u] : 0.0f;
    half2_t hp[5];
    {
        float hb[10];
#pragma unroll
        for (int j = 0; j < 10; j++) hb[j] = h0[e * HH + j];
#pragma unroll
        for (int p = 0; p < 5; p++) hp[p] = __builtin_amdgcn_cvt_pkrtz(hb[2 * p], hb[2 * p + 1]);
    }

    const float4* xq  = (const float4*)(x + (size_t)e * TT);
    float4*       ob4 = (float4*)(out + (size_t)e * TT);

    float4 xc = xq[0];
    float4 outv;
    float xprev = 0.0f;   // x of previous step (first regressor result is discarded)

    for (int gb = 0; gb < TT / 4; gb++) {
        const int gbn = (gb + 1) & (TT / 4 - 1);   // wrap: last prefetch reads block 0
        float4 xn = xq[gbn];

#pragma unroll
        for (int r4 = 0; r4 < 4; r4++) {
            const float xv = (r4 == 0) ? xc.x : (r4 == 1) ? xc.y : (r4 == 2) ? xc.z : xc.w;

            // ---- gates(t): 4 lane-local rows, pre-scaled accumulators ----
            float gi = fmaf(xv, wii, bi);
            float gf = fmaf(xv, wif, bf);
            float gg = fmaf(xv, wig, bg);
            float go = fmaf(xv, wio, bo);
#pragma unroll
            for (int p = 0; p < 5; p++) {
                gi = __builtin_amdgcn_fdot2(hp[p], Wi[p], gi, false);
                gf = __builtin_amdgcn_fdot2(hp[p], Wf[p], gf, false);
                gg = __builtin_amdgcn_fdot2(hp[p], Wg[p], gg, false);
                go = __builtin_amdgcn_fdot2(hp[p], Wo[p], go, false);
            }

            // ---- regressor(t-1): hp still holds h(t-1); fills the act-chain stall ----
            {
                float a = b1r;
#pragma unroll
                for (int p = 0; p < 5; p++)
                    a = __builtin_amdgcn_fdot2(hp[p], W1p[p], a, false);
                float part = fmaf(fmaxf(a, 0.0f), W2r, seedb);
                part += dpp_<QP_XOR1>(part);
                part += dpp_<QP_XOR2>(part);
                part += dpp_<ROR4>(part);
                part += dpp_<ROR8>(part);
                const float s = part + xprev;
                // slot = (step t-1) & 3 = (r4+3)&3
                if (r4 == 0) {
                    outv.w = s;
                    if (gb && l == 0) ob4[gb - 1] = outv;
                }
                else if (r4 == 1) outv.x = s;
                else if (r4 == 2) outv.y = s;
                else outv.z = s;
            }

            // ---- acts + c/h update ----
            const float A = exp2_(gi);
            const float F = exp2_(gf);
            const float G = exp2_(gg);
            const float O = exp2_(go);
            const float af = rcp_(1.0f + F);
            const float q  = (1.0f - G) * rcp_((1.0f + A) * (1.0f + G));
            const float cn = fmaf(af, c, q);
            c = cn;
            const float T  = exp2_(cn * (-2.0f * L2E));
            const float hq = (1.0f - T) * rcp_((1.0f + O) * (1.0f + T));

            // ---- pure-DPP packed h broadcast (trimmed: banks 0-2 only) ----
            const float hq_p = dpp_<QP_XOR1>(hq);
            // even lanes (the only broadcast sources) get (h_2j, h_2j+1)
            half2_t pkh = __builtin_amdgcn_cvt_pkrtz(hq, hq_p);
            const int pk = *(const int*)&pkh;
            const int A_ = dppi_<QP_B0>(0, pk);   // quad q sees pk_{2q}
            const int B_ = dppi_<QP_B2>(0, pk);   // quad q sees pk_{2q+1}
            int h0i = A_;                          // pk0 @ quad0
            h0i = dppi_<ROR12, 0x2>(h0i, A_);
            h0i = dppi_<ROR8,  0x4>(h0i, A_);
            int h1i = B_;                          // pk1 @ quad0
            h1i = dppi_<ROR12, 0x2>(h1i, B_);
            h1i = dppi_<ROR8,  0x4>(h1i, B_);
            int h2i = A_;                          // pk2 @ quad1
            h2i = dppi_<ROR4,  0x1>(h2i, A_);
            h2i = dppi_<ROR12, 0x4>(h2i, A_);
            int h3i = B_;                          // pk3 @ quad1
            h3i = dppi_<ROR4,  0x1>(h3i, B_);
            h3i = dppi_<ROR12, 0x4>(h3i, B_);
            int h4i = A_;                          // pk4 @ quad2
            h4i = dppi_<ROR8,  0x1>(h4i, A_);
            h4i = dppi_<ROR4,  0x2>(h4i, A_);
            hp[0] = *(const half2_t*)&h0i;
            hp[1] = *(const half2_t*)&h1i;
            hp[2] = *(const half2_t*)&h2i;
            hp[3] = *(const half2_t*)&h3i;
            hp[4] = *(const half2_t*)&h4i;

            xprev = xv;
        }

        xc = xn;
    }

    // ---- epilogue: regressor for step TT-1 (hp = h(TT-1), xprev = x(TT-1)) ----
    {
        float a = b1r;
#pragma unroll
        for (int p = 0; p < 5; p++)
            a = __builtin_amdgcn_fdot2(hp[p], W1p[p], a, false);
        float part = fmaf(fmaxf(a, 0.0f), W2r, seedb);
        part += dpp_<QP_XOR1>(part);
        part += dpp_<QP_XOR2>(part);
        part += dpp_<ROR4>(part);
        part += dpp_<ROR8>(part);
        outv.w = part + xprev;
        if (l == 0) ob4[TT / 4 - 1] = outv;
    }
}

extern "C" void kernel_launch(void* const* d_in, const int* in_sizes, int n_in,
                              void* d_out, int out_size, void* d_ws, size_t ws_size,
                              hipStream_t stream) {
    const float* x    = (const float*)d_in[0];
    const float* h0   = (const float*)d_in[1];
    const float* c0   = (const float*)d_in[2];
    const float* W_ih = (const float*)d_in[3];
    const float* W_hh = (const float*)d_in[4];
    const float* b_ih = (const float*)d_in[5];
    const float* b_hh = (const float*)d_in[6];
    const float* W1   = (const float*)d_in[7];
    const float* b1   = (const float*)d_in[8];
    const float* W2   = (const float*)d_in[9];
    const float* b2   = (const float*)d_in[10];
    float* out = (float*)d_out;

    dim3 grid(BB * 16 / 64);   // 1024 blocks: 4 waves/CU (1 per SIMD)
    dim3 block(64);
    lstm16pipe_kernel<<<grid, block, 0, stream>>>(x, h0, c0, W_ih, W_hh, b_ih, b_hh,
                                                  W1, b1, W2, b2, out);
}